// Round 7
// baseline (95.569 us; speedup 1.0000x reference)
//
#include <hip/hip_runtime.h>

// Problem constants: B=4, L=512, D=128, C=128
#define NB 4
#define SL 512
#define DD 128
#define CC 128

__device__ __forceinline__ float fexp2(float x) { return __builtin_amdgcn_exp2f(x); }
__device__ __forceinline__ float frcp(float x)  { return __builtin_amdgcn_rcpf(x); }

// Kernel 1 (v7): F ONLY.  F[b][c][l] = exp2(K2 * (inps @ wei_x))^T.
// E is now computed inside attn (each block needs only its own 4 rows),
// so proj's E half is deleted: half the dot products of the proven v1.
// 512 blocks x 256 thr; block covers 4 L-rows; h=tid>>7 picks the row
// pair -> same proven 1:2 load:fma ratio and float2 writes as v1.
__global__ __launch_bounds__(256) void projF_kernel(
    const float* __restrict__ inps, const float* __restrict__ wei_x,
    float* __restrict__ F)
{
    const float K2 = 2.8853900817779268f;  // 2*log2(e)
    const int row0 = blockIdx.x * 4;       // global row = b*SL + l
    const int b    = row0 >> 9;
    const int l0   = row0 & 511;
    const int c    = threadIdx.x & 127;
    const int h    = threadIdx.x >> 7;     // wave-uniform row-pair select

    const float* r0 = inps + (size_t)(row0 + 2 * h) * DD;  // uniform -> s_load
    const float* r1 = r0 + DD;

    float a0 = 0.f, a1 = 0.f;
    #pragma unroll 8
    for (int k = 0; k < DD; ++k) {
        float w = wei_x[k * CC + c];       // coalesced across c
        a0 = fmaf(r0[k], w, a0);
        a1 = fmaf(r1[k], w, a1);
    }
    float2 v = {fexp2(K2 * a0), fexp2(K2 * a1)};
    *reinterpret_cast<float2*>(&F[((size_t)b * CC + c) * SL + l0 + 2 * h]) = v;
}

// Kernel 2 (v7): one block per (b, 4 rows of i). 512 blocks x 512 thr,
// (512,4) -> 128-VGPR cap, 2 blocks/CU (grid caps at 2/CU anyway).
// Occupancy experiments r0/r5/r6 all flat at ~91 -> phase B is bound by
// per-CU serial pipes (LDS + L1/L2 + trans), not latency coverage. So:
//  - Phase P: compute OUR 4 E-rows locally (131 KFLOP) -> proj halved,
//    E round-trip + phase A deleted.
//  - Phase B on j-QUADS: float4 F loads -> F-load instrs AND broadcast
//    ds_read_b128s halved (64 -> 32/thread). Same FLOPs, same bytes.
//  - Phase C on all 512 threads: 1 thread per (j-quad, row).
__global__ __launch_bounds__(512, 4) void attn_kernel(
    const float* __restrict__ inps, const float* __restrict__ wei_t,
    const float* __restrict__ bxh,  const float* __restrict__ wei_a,
    const float* __restrict__ F,    float* __restrict__ out)
{
    __shared__ float4 upk[CC];             // E quads {E[i0..i0+3, c]}  (2 KB)
    __shared__ float pool[4 * 128 * 17];   // 34.8 KB: c-merge (stride 17), then D partials
    __shared__ float scT[SL * 4];          // a[i][j] stored [j][4]      (8 KB)
    __shared__ float redw[4 * 2];          // 4 rows x 2 waves-per-row

    const float K2 = 2.8853900817779268f;  // 2*log2(e)
    const int blk = blockIdx.x;            // 512 blocks
    const int b   = blk >> 7;
    const int i0  = (blk & 127) * 4;
    const int bi0 = b * SL + i0;
    const int tid = threadIdx.x;

    // Phase P: E rows for THIS block, straight into upk (no memory round-trip).
    {
        const int r = tid >> 7;            // 0..3 (wave-uniform: wave w -> r=w>>1)
        const int c = tid & 127;
        const float* rp = inps + (size_t)(bi0 + r) * DD;   // uniform -> s_load
        float acc = 0.f;
        #pragma unroll 8
        for (int k = 0; k < DD; ++k)
            acc = fmaf(rp[k], wei_t[k * CC + c], acc);     // coalesced across c
        ((float*)&upk[c])[r] = fexp2(K2 * (acc + bxh[c]));
    }
    __syncthreads();                       // barrier 1: upk ready

    // Phase B: thread (jg = tid&127, cq = tid>>7) covers 4 j x 32 c x 4 i.
    // Rational pairing per c-pair: one v_rcp per two c-terms (as proven).
    const int jg = tid & 127;
    const int cq = tid >> 7;               // wave-uniform
    const int j0 = jg * 4;
    const int c0 = cq * 32;
    const float* fb = F + ((size_t)b * CC + c0) * SL + j0;
    const float4* up = upk + c0;
    const float* wa = wei_a + c0;          // uniform -> s_load (K$ hot)
    float ac[4][4] = {{0.f,0.f,0.f,0.f},{0.f,0.f,0.f,0.f},
                      {0.f,0.f,0.f,0.f},{0.f,0.f,0.f,0.f}};
    #pragma unroll 2
    for (int cp = 0; cp < 16; ++cp) {
        float4 f0 = *reinterpret_cast<const float4*>(&fb[(size_t)(2 * cp) * SL]);
        float4 f1 = *reinterpret_cast<const float4*>(&fb[(size_t)(2 * cp + 1) * SL]);
        float4 u0 = up[2 * cp];            // broadcast ds_read_b128 (uniform addr)
        float4 u1 = up[2 * cp + 1];
        float wa0 = wa[2 * cp], wa1 = wa[2 * cp + 1];
        const float* u0p = reinterpret_cast<const float*>(&u0);
        const float* u1p = reinterpret_cast<const float*>(&u1);
        const float* f0p = reinterpret_cast<const float*>(&f0);
        const float* f1p = reinterpret_cast<const float*>(&f1);
        #pragma unroll
        for (int i = 0; i < 4; ++i) {
            #pragma unroll
            for (int j = 0; j < 4; ++j) {
                float ax = fmaf(u0p[i], f0p[j], 1.0f);
                float bx = fmaf(u1p[i], f1p[j], 1.0f);
                float num = fmaf(wa0, bx, wa1 * ax);
                ac[i][j] = fmaf(num, frcp(ax * bx), ac[i][j]);
            }
        }
    }
    {   // park all 4 c-quarters (stride 17: gcd(17,32)=1 -> 2-way = free)
        float* m = &pool[cq * 2176 + jg * 17];
        #pragma unroll
        for (int i = 0; i < 4; ++i)
            #pragma unroll
            for (int j = 0; j < 4; ++j)
                m[i * 4 + j] = ac[i][j];
    }
    __syncthreads();                       // barrier 2: partials parked

    // Phase C: ALL 512 threads; thread (jg, i=cq) merges 4 segments,
    // exps, row-reduces (2 waves per row), normalizes, stores scT[j][4].
    {
        float s0 = 0.f, s1 = 0.f, s2 = 0.f, s3 = 0.f;
        #pragma unroll
        for (int seg = 0; seg < 4; ++seg) {
            const float* m = &pool[seg * 2176 + jg * 17 + cq * 4];
            s0 += m[0]; s1 += m[1]; s2 += m[2]; s3 += m[3];
        }
        const float KE = -2.8853900817779268f;  // -2*log2(e)
        float e0 = fexp2(s0 * KE), e1 = fexp2(s1 * KE);
        float e2 = fexp2(s2 * KE), e3 = fexp2(s3 * KE);
        float p = (e0 + e1) + (e2 + e3);
        #pragma unroll
        for (int off = 32; off > 0; off >>= 1)
            p += __shfl_xor(p, off, 64);
        if ((tid & 63) == 0) redw[cq * 2 + ((tid >> 6) & 1)] = p;
        __syncthreads();                   // barrier 3: redw ready
        float S  = redw[cq * 2] + redw[cq * 2 + 1];
        float rS = frcp(S + 1e-7f);
        scT[(j0    ) * 4 + cq] = e0 * rS;
        scT[(j0 + 1) * 4 + cq] = e1 * rS;
        scT[(j0 + 2) * 4 + cq] = e2 * rS;
        scT[(j0 + 3) * 4 + cq] = e3 * rS;
    }
    __syncthreads();                       // barrier 4: scT ready, pool free

    // Phase D: a @ inps partials, all 512 threads (proven r5 shape).
    {
        const int dq = (tid & 31) * 4;
        const int jq = tid >> 5;           // 0..15, 32 j each
        const float* ibase = inps + (size_t)b * SL * DD;
        float4 acc0 = {0,0,0,0}, acc1 = {0,0,0,0}, acc2 = {0,0,0,0}, acc3 = {0,0,0,0};
        const int jb = jq * 32;
        #pragma unroll 4
        for (int jj = 0; jj < 32; ++jj) {
            int jx = jb + jj;
            float4 v  = *reinterpret_cast<const float4*>(ibase + (size_t)jx * DD + dq);
            float4 a4 = *reinterpret_cast<const float4*>(&scT[jx * 4]);  // broadcast
            acc0.x = fmaf(a4.x, v.x, acc0.x); acc0.y = fmaf(a4.x, v.y, acc0.y);
            acc0.z = fmaf(a4.x, v.z, acc0.z); acc0.w = fmaf(a4.x, v.w, acc0.w);
            acc1.x = fmaf(a4.y, v.x, acc1.x); acc1.y = fmaf(a4.y, v.y, acc1.y);
            acc1.z = fmaf(a4.y, v.z, acc1.z); acc1.w = fmaf(a4.y, v.w, acc1.w);
            acc2.x = fmaf(a4.z, v.x, acc2.x); acc2.y = fmaf(a4.z, v.y, acc2.y);
            acc2.z = fmaf(a4.z, v.z, acc2.z); acc2.w = fmaf(a4.z, v.w, acc2.w);
            acc3.x = fmaf(a4.w, v.x, acc3.x); acc3.y = fmaf(a4.w, v.y, acc3.y);
            acc3.z = fmaf(a4.w, v.z, acc3.z); acc3.w = fmaf(a4.w, v.w, acc3.w);
        }
        *reinterpret_cast<float4*>(&pool[(0 * 16 + jq) * DD + dq]) = acc0;
        *reinterpret_cast<float4*>(&pool[(1 * 16 + jq) * DD + dq]) = acc1;
        *reinterpret_cast<float4*>(&pool[(2 * 16 + jq) * DD + dq]) = acc2;
        *reinterpret_cast<float4*>(&pool[(3 * 16 + jq) * DD + dq]) = acc3;
    }
    __syncthreads();                       // barrier 5

    // Phase E: reduce 16 partials per (i, d), write out.
    {
        int i = tid >> 7, d = tid & 127;   // 4 rows x 128 d
        float sum = 0.f;
        #pragma unroll
        for (int q = 0; q < 16; ++q) sum += pool[(i * 16 + q) * DD + d];
        out[(size_t)(bi0 + i) * DD + d] = sum;
    }
}

extern "C" void kernel_launch(void* const* d_in, const int* in_sizes, int n_in,
                              void* d_out, int out_size, void* d_ws, size_t ws_size,
                              hipStream_t stream) {
    const float* inps  = (const float*)d_in[0];  // [B, L, D]
    const float* wei_t = (const float*)d_in[1];  // [D, C]
    const float* wei_x = (const float*)d_in[2];  // [D, C]
    const float* bxh   = (const float*)d_in[3];  // [C]
    const float* wei_a = (const float*)d_in[4];  // [C]
    // d_in[5] = bxa (scalar): uniform shift before softmax -> dropped.
    float* out = (float*)d_out;                  // [B, L, D] fp32

    float* F = (float*)d_ws;                     // [B, C, L]  1 MB (E is gone)

    projF_kernel<<<NB * SL / 4, 256, 0, stream>>>(inps, wei_x, F);
    attn_kernel<<<NB * SL / 4, 512, 0, stream>>>(inps, wei_t, bxh, wei_a, F, out);
}

// Round 8
// 90.996 us; speedup vs baseline: 1.0503x; 1.0503x over previous
//
#include <hip/hip_runtime.h>

// Problem constants: B=4, L=512, D=128, C=128
#define NB 4
#define SL 512
#define DD 128
#define CC 128

__device__ __forceinline__ float fexp2(float x) { return __builtin_amdgcn_exp2f(x); }
__device__ __forceinline__ float frcp(float x)  { return __builtin_amdgcn_rcpf(x); }

// Kernel 1: projections, EXPONENTIATED (trans factorization):
//   E  [B*L, C]  = exp2( K2 * (inps @ wei_t + bxh) )
//   F  [B, C, L] = exp2( K2 * (inps @ wei_x) )^T
// v1 (round-0 proven, best measured): 2 rows/block, 256 threads,
// 1024 blocks = 4 blocks/CU = 4 waves/SIMD.
// SESSION NOTE (r0-r7): this problem's total is dominated by a fixed
// ~41 us harness workspace re-poison fill + ~15-20 us launch overhead.
// Kernel-side levers (occupancy 4/6/8 w/SIMD, VGPR 64/85/128, load-count
// halving, E-local vs E-staged) all land 91 +/- 3 us. This file is the
// best measured configuration (r5: 90.7 us).
__global__ __launch_bounds__(256) void proj_kernel(
    const float* __restrict__ inps, const float* __restrict__ wei_t,
    const float* __restrict__ wei_x, const float* __restrict__ bxh,
    float* __restrict__ E, float* __restrict__ F)
{
    const float K2 = 2.8853900817779268f;  // 2*log2(e)
    const int row0 = blockIdx.x * 2;       // global row = b*SL + i
    const int b    = row0 >> 9;
    const int i0   = row0 & 511;
    const int c    = threadIdx.x & 127;
    const int sel  = threadIdx.x >> 7;     // wave-uniform: waves 0-1 wei_t, 2-3 wei_x

    const float* W  = sel ? wei_x : wei_t;
    const float* r0 = inps + (size_t)row0 * DD;   // uniform -> s_load
    const float* r1 = r0 + DD;

    float a0 = 0.f, a1 = 0.f;
    #pragma unroll 8
    for (int k = 0; k < DD; ++k) {
        float w = W[k * CC + c];           // coalesced across c
        a0 = fmaf(r0[k], w, a0);
        a1 = fmaf(r1[k], w, a1);
    }

    if (sel == 0) {
        float bb = bxh[c];
        E[(size_t)(row0 + 0) * CC + c] = fexp2(K2 * (a0 + bb));
        E[(size_t)(row0 + 1) * CC + c] = fexp2(K2 * (a1 + bb));
    } else {
        float2 v = {fexp2(K2 * a0), fexp2(K2 * a1)};
        *reinterpret_cast<float2*>(&F[((size_t)b * CC + c) * SL + i0]) = v;
    }
}

// Kernel 2 (r5 proven, 90.7 us): one block per (b, 4 rows of i).
// 512 blocks x 512 threads, (512,4) -> 2 blocks/CU, 4 waves/SIMD.
// Phase B: c-half per thread (64 c, 32 iters), rational pairing (one
// v_rcp per two c-terms), 2-way LDS merge (stride 9 -> conflict-free).
// Softmax max-pass dropped (scores bounded, sum >= 1 -> +eps matches
// reference to <= 1e-7 relative).
__global__ __launch_bounds__(512, 4) void attn_kernel(
    const float* __restrict__ inps, const float* __restrict__ wei_a,
    const float* __restrict__ E, const float* __restrict__ F,
    float* __restrict__ out)
{
    __shared__ float4 upk[CC];             // E quads {E[i0..i0+3, c]}  (2 KB)
    __shared__ float pool[4 * 16 * DD];    // 32 KB: c-merge (B/C), then phase-D partials
    __shared__ float scT[SL * 4];          // a[i][j] stored [j][4]      (8 KB)
    __shared__ float redw[4 * 4];          // 4 rows x 4 waves

    const int blk = blockIdx.x;            // 512 blocks
    const int b   = blk >> 7;
    const int i0  = (blk & 127) * 4;
    const int bi0 = b * SL + i0;
    const int tid = threadIdx.x;
    const int jt  = tid & 255;             // j-pair index
    const int ch  = tid >> 8;              // c-half (wave-uniform)
    const int j0  = jt * 2;

    // Phase A: stage the four block-uniform E rows as quads (128 threads)
    if (tid < CC) {
        float4 u;
        u.x = E[(size_t)(bi0 + 0) * CC + tid];
        u.y = E[(size_t)(bi0 + 1) * CC + tid];
        u.z = E[(size_t)(bi0 + 2) * CC + tid];
        u.w = E[(size_t)(bi0 + 3) * CC + tid];
        upk[tid] = u;
    }
    __syncthreads();                       // barrier 1

    // Phase B: partial s over this thread's 64-c half, 4 i's x 2 j's.
    const int c0 = ch * 64;
    const float* fb = F + ((size_t)b * CC + c0) * SL + j0;
    const float4* up = upk + c0;
    const float* wa = wei_a + c0;          // uniform -> s_load (K$ hot)
    float sx[4] = {0.f, 0.f, 0.f, 0.f};
    float sy[4] = {0.f, 0.f, 0.f, 0.f};
    #pragma unroll 4
    for (int cp = 0; cp < 32; ++cp) {
        float2 f0 = *reinterpret_cast<const float2*>(&fb[(size_t)(2 * cp) * SL]);
        float2 f1 = *reinterpret_cast<const float2*>(&fb[(size_t)(2 * cp + 1) * SL]);
        float4 u0 = up[2 * cp];            // broadcast ds_read_b128
        float4 u1 = up[2 * cp + 1];
        float wa0 = wa[2 * cp], wa1 = wa[2 * cp + 1];
        const float* u0p = reinterpret_cast<const float*>(&u0);
        const float* u1p = reinterpret_cast<const float*>(&u1);
        #pragma unroll
        for (int i = 0; i < 4; ++i) {
            float ax = fmaf(u0p[i], f0.x, 1.0f);
            float bx = fmaf(u1p[i], f1.x, 1.0f);
            float numx = fmaf(wa0, bx, wa1 * ax);
            sx[i] = fmaf(numx, frcp(ax * bx), sx[i]);
            float ay = fmaf(u0p[i], f0.y, 1.0f);
            float by = fmaf(u1p[i], f1.y, 1.0f);
            float numy = fmaf(wa0, by, wa1 * ay);
            sy[i] = fmaf(numy, frcp(ay * by), sy[i]);
        }
    }

    // Park upper-half partials (stride 9: gcd(9,32)=1 -> 2-way max = free).
    if (ch == 1) {
        float* m = &pool[jt * 9];
        #pragma unroll
        for (int i = 0; i < 4; ++i) { m[i] = sx[i]; m[4 + i] = sy[i]; }
    }
    __syncthreads();                       // barrier 2: partials parked

    // Phase C (lower-half threads, 4 waves): merge + exp + row-sum + norm.
    if (ch == 0) {
        {
            const float* m = &pool[jt * 9];
            #pragma unroll
            for (int i = 0; i < 4; ++i) { sx[i] += m[i]; sy[i] += m[4 + i]; }
        }
        const float KE = -2.8853900817779268f;  // -2*log2(e)
        float ex[4], ey[4];
        const int lane = tid & 63, wv = tid >> 6;   // wv in 0..3
        #pragma unroll
        for (int i = 0; i < 4; ++i) {
            ex[i] = fexp2(sx[i] * KE);
            ey[i] = fexp2(sy[i] * KE);
            float t = ex[i] + ey[i];
            #pragma unroll
            for (int off = 32; off > 0; off >>= 1)
                t += __shfl_xor(t, off, 64);
            if (lane == 0) redw[i * 4 + wv] = t;
        }
        __syncthreads();                   // barrier 3
        float4 av0, av1;
        {
            float S0 = redw[0] + redw[1] + redw[2] + redw[3];
            float S1 = redw[4] + redw[5] + redw[6] + redw[7];
            float S2 = redw[8] + redw[9] + redw[10] + redw[11];
            float S3 = redw[12] + redw[13] + redw[14] + redw[15];
            float r0 = frcp(S0 + 1e-7f), r1 = frcp(S1 + 1e-7f);
            float r2 = frcp(S2 + 1e-7f), r3 = frcp(S3 + 1e-7f);
            av0 = make_float4(ex[0] * r0, ex[1] * r1, ex[2] * r2, ex[3] * r3);
            av1 = make_float4(ey[0] * r0, ey[1] * r1, ey[2] * r2, ey[3] * r3);
        }
        *reinterpret_cast<float4*>(&scT[j0 * 4])     = av0;  // a[*][j0]
        *reinterpret_cast<float4*>(&scT[j0 * 4 + 4]) = av1;  // a[*][j0+1]
    } else {
        __syncthreads();                   // barrier 3 (match)
    }
    __syncthreads();                       // barrier 4: scT ready, pool free

    // Phase D: a @ inps partials, all 512 threads.
    {
        const int dq = (tid & 31) * 4;
        const int jq = tid >> 5;           // 0..15, 32 j each
        const float* ibase = inps + (size_t)b * SL * DD;
        float4 acc0 = {0,0,0,0}, acc1 = {0,0,0,0}, acc2 = {0,0,0,0}, acc3 = {0,0,0,0};
        const int jb = jq * 32;
        #pragma unroll 4
        for (int jj = 0; jj < 32; ++jj) {
            int jx = jb + jj;
            float4 v  = *reinterpret_cast<const float4*>(ibase + (size_t)jx * DD + dq);
            float4 a4 = *reinterpret_cast<const float4*>(&scT[jx * 4]);  // broadcast
            acc0.x = fmaf(a4.x, v.x, acc0.x); acc0.y = fmaf(a4.x, v.y, acc0.y);
            acc0.z = fmaf(a4.x, v.z, acc0.z); acc0.w = fmaf(a4.x, v.w, acc0.w);
            acc1.x = fmaf(a4.y, v.x, acc1.x); acc1.y = fmaf(a4.y, v.y, acc1.y);
            acc1.z = fmaf(a4.y, v.z, acc1.z); acc1.w = fmaf(a4.y, v.w, acc1.w);
            acc2.x = fmaf(a4.z, v.x, acc2.x); acc2.y = fmaf(a4.z, v.y, acc2.y);
            acc2.z = fmaf(a4.z, v.z, acc2.z); acc2.w = fmaf(a4.z, v.w, acc2.w);
            acc3.x = fmaf(a4.w, v.x, acc3.x); acc3.y = fmaf(a4.w, v.y, acc3.y);
            acc3.z = fmaf(a4.w, v.z, acc3.z); acc3.w = fmaf(a4.w, v.w, acc3.w);
        }
        *reinterpret_cast<float4*>(&pool[(0 * 16 + jq) * DD + dq]) = acc0;
        *reinterpret_cast<float4*>(&pool[(1 * 16 + jq) * DD + dq]) = acc1;
        *reinterpret_cast<float4*>(&pool[(2 * 16 + jq) * DD + dq]) = acc2;
        *reinterpret_cast<float4*>(&pool[(3 * 16 + jq) * DD + dq]) = acc3;
    }
    __syncthreads();                       // barrier 5

    // Phase E: reduce 16 partials per (i, d), write out.
    {
        int i = tid >> 7, d = tid & 127;   // 4 rows x 128 d
        float sum = 0.f;
        #pragma unroll
        for (int q = 0; q < 16; ++q) sum += pool[(i * 16 + q) * DD + d];
        out[(size_t)(bi0 + i) * DD + d] = sum;
    }
}

extern "C" void kernel_launch(void* const* d_in, const int* in_sizes, int n_in,
                              void* d_out, int out_size, void* d_ws, size_t ws_size,
                              hipStream_t stream) {
    const float* inps  = (const float*)d_in[0];  // [B, L, D]
    const float* wei_t = (const float*)d_in[1];  // [D, C]
    const float* wei_x = (const float*)d_in[2];  // [D, C]
    const float* bxh   = (const float*)d_in[3];  // [C]
    const float* wei_a = (const float*)d_in[4];  // [C]
    // d_in[5] = bxa (scalar): uniform shift before softmax -> dropped.
    float* out = (float*)d_out;                  // [B, L, D] fp32

    float* E = (float*)d_ws;                     // [B*L, C]   1 MB
    float* F = E + (size_t)NB * SL * CC;         // [B, C, L]  1 MB

    proj_kernel<<<NB * SL / 2, 256, 0, stream>>>(inps, wei_t, wei_x, bxh, E, F);
    attn_kernel<<<NB * SL / 4, 512, 0, stream>>>(inps, wei_a, E, F, out);
}